// Round 3
// baseline (188.751 us; speedup 1.0000x reference)
//
#include <hip/hip_runtime.h>
#include <math.h>

#define BB 4
#define CIN 128
#define LL 2048
#define HH 8
#define CH 32
#define HID 256

typedef __attribute__((ext_vector_type(8))) __bf16 bf16x8;
typedef __attribute__((ext_vector_type(4))) float f32x4;

static __device__ __forceinline__ unsigned int f2bf(float f) {
    union { __bf16 b; unsigned short s; } u;
    u.b = (__bf16)f;
    return (unsigned int)u.s;
}
static __device__ __forceinline__ float bf2f(unsigned int s) {
    union { float f; unsigned int u; } x;
    x.u = s << 16;
    return x.f;
}

// ---------------------------------------------------------------------------
// Kernel 1: QKV 1x1 conv -> bf16 buffers.
// Q: [bh][l][d] bf16, pre-scaled by 1/sqrt(L).  K: [bh][l][d] bf16.
// V: transposed [bh][d][l] bf16.
// ---------------------------------------------------------------------------
__global__ __launch_bounds__(256) void qkv_kernel(
        const float* __restrict__ x, const float* __restrict__ w_qkv,
        const float* __restrict__ b_qkv,
        unsigned short* __restrict__ qb, unsigned short* __restrict__ kb,
        unsigned short* __restrict__ vtb) {
    __shared__ float wl[32 * 128];
    __shared__ float tr[32 * 65];
    const int t = threadIdx.x;
    const int lt = blockIdx.x;           // 0..31
    const int g  = blockIdx.y;           // 0..23 : sel*8 + h
    const int b  = blockIdx.z;
    const int sel = g >> 3, h = g & 7;
    const int obase = sel * 256 + h * 32;
    const int l0 = lt * 64;

    const float4* wsrc = (const float4*)(w_qkv + (size_t)obase * CIN);
    float4* wdst = (float4*)wl;
    #pragma unroll
    for (int r = 0; r < 4; ++r) wdst[r * 256 + t] = wsrc[r * 256 + t];
    __syncthreads();

    const int ll = t & 63, og = t >> 6;
    float acc[8] = {0.f,0.f,0.f,0.f,0.f,0.f,0.f,0.f};
    const float* xp = x + (size_t)b * CIN * LL + l0 + ll;
    for (int i = 0; i < CIN; i += 4) {
        float x0 = xp[(size_t)(i+0) * LL];
        float x1 = xp[(size_t)(i+1) * LL];
        float x2 = xp[(size_t)(i+2) * LL];
        float x3 = xp[(size_t)(i+3) * LL];
        #pragma unroll
        for (int j = 0; j < 8; ++j) {
            float4 w4 = *(const float4*)(wl + (og * 8 + j) * 128 + i);
            acc[j] += w4.x * x0 + w4.y * x1 + w4.z * x2 + w4.w * x3;
        }
    }
    const float scale = (sel == 0) ? 0.02209708691207961f : 1.0f;  // 1/sqrt(2048)
    #pragma unroll
    for (int j = 0; j < 8; ++j) {
        int oc = og * 8 + j;
        tr[oc * 65 + ll] = (acc[j] + b_qkv[obase + oc]) * scale;   // [c][l]
    }
    __syncthreads();
    if (sel == 2) {
        unsigned short* dst = vtb + ((size_t)(b * HH + h) * CH) * LL + l0;
        #pragma unroll
        for (int r = 0; r < 8; ++r) {
            int flat = r * 256 + t;           // c*64 + l
            int c = flat >> 6, l = flat & 63;
            dst[(size_t)c * LL + l] = (unsigned short)f2bf(tr[c * 65 + l]);
        }
    } else {
        unsigned short* dst = (sel == 0 ? qb : kb)
                              + ((size_t)(b * HH + h) * LL + l0) * CH;
        #pragma unroll
        for (int r = 0; r < 8; ++r) {
            int flat = r * 256 + t;           // lr*32 + c
            int c = flat & 31, lr = flat >> 5;
            dst[flat] = (unsigned short)f2bf(tr[c * 65 + lr]);
        }
    }
}

// ---------------------------------------------------------------------------
// Kernel 2: softmax denominators via MFMA, then scale V^T in place:
// vtb[bh][d][q] *= 1/sum_a exp(q . k_a).  Block owns (bh, 64-q tile).
// XCD swizzle: block id&7 selects xcd; each xcd owns 4 bh.
// ---------------------------------------------------------------------------
__global__ __launch_bounds__(256) void denom_mfma(
        const unsigned short* __restrict__ qb,
        const unsigned short* __restrict__ kb,
        unsigned short* __restrict__ vtb) {
    __shared__ float zz[64];
    const int t = threadIdx.x, wave = t >> 6, lane = t & 63;
    const int id = blockIdx.x;
    const int bh = (id & 7) * 4 + ((id >> 3) >> 5);
    const int qt = (id >> 3) & 31;
    const int q0 = qt * 64 + wave * 16;
    const int r = lane & 15, g = lane >> 4;

    bf16x8 afrag = *(const bf16x8*)(qb + ((size_t)bh * LL + q0 + r) * CH + 8 * g);
    const unsigned short* kp = kb + ((size_t)bh * LL + r) * CH + 8 * g;

    float z0 = 0.f, z1 = 0.f, z2 = 0.f, z3 = 0.f;
    const f32x4 zero = {0.f, 0.f, 0.f, 0.f};
    for (int a0 = 0; a0 < LL; a0 += 64) {
        #pragma unroll
        for (int s = 0; s < 4; ++s) {
            bf16x8 bfrag = *(const bf16x8*)(kp + (size_t)(a0 + s * 16) * CH);
            f32x4 d = __builtin_amdgcn_mfma_f32_16x16x32_bf16(afrag, bfrag, zero, 0, 0, 0);
            z0 += __expf(d[0]); z1 += __expf(d[1]);
            z2 += __expf(d[2]); z3 += __expf(d[3]);
        }
    }
    #pragma unroll
    for (int m = 1; m < 16; m <<= 1) {
        z0 += __shfl_xor(z0, m); z1 += __shfl_xor(z1, m);
        z2 += __shfl_xor(z2, m); z3 += __shfl_xor(z3, m);
    }
    if (r == 0) {
        // rows q0 + 4g + i (block-local: wave*16 + 4g + i)
        *(float4*)&zz[wave * 16 + 4 * g] =
            make_float4(1.f / z0, 1.f / z1, 1.f / z2, 1.f / z3);
    }
    __syncthreads();

    // scale vtb[bh][d][qt*64 .. +63] by zz[qlocal]; 256 thr x 8 elems = 32x64
    const int d = t >> 3, qo = (t & 7) * 8;
    unsigned short* vrow = vtb + ((size_t)bh * CH + d) * LL + qt * 64 + qo;
    uint4 v = *(const uint4*)vrow;
    const float* zp = zz + qo;
    unsigned int w0, w1, w2, w3;
    w0 = f2bf(bf2f(v.x & 0xFFFFu) * zp[0]) | (f2bf(bf2f(v.x >> 16) * zp[1]) << 16);
    w1 = f2bf(bf2f(v.y & 0xFFFFu) * zp[2]) | (f2bf(bf2f(v.y >> 16) * zp[3]) << 16);
    w2 = f2bf(bf2f(v.z & 0xFFFFu) * zp[4]) | (f2bf(bf2f(v.z >> 16) * zp[5]) << 16);
    w3 = f2bf(bf2f(v.w & 0xFFFFu) * zp[6]) | (f2bf(bf2f(v.w >> 16) * zp[7]) << 16);
    *(uint4*)vrow = make_uint4(w0, w1, w2, w3);
}

// ---------------------------------------------------------------------------
// Kernel 3: attn^T via MFMA, no LDS.  attnT[b][h*32+d][a] = sum_q P[q,a] V'[q,d]
// (V' pre-scaled by invz).  Wave owns 16 a-cols; loop q by 32.
// P^T A-fragment built in-register via ds_bpermute lane permutation.
// ---------------------------------------------------------------------------
__global__ __launch_bounds__(256) void attn_mfma(
        const unsigned short* __restrict__ qb,
        const unsigned short* __restrict__ kb,
        const unsigned short* __restrict__ vtb,
        float* __restrict__ attnT) {
    const int t = threadIdx.x, wave = t >> 6, lane = t & 63;
    const int r = lane & 15, g = lane >> 4;
    const int id = blockIdx.x;
    const int bh = (id & 7) * 4 + ((id >> 3) >> 5);
    const int at = (id >> 3) & 31;
    const int b = bh >> 3, h = bh & 7;
    const int a0 = at * 64 + wave * 16;

    // loop-invariant K fragment (B of S-MFMA): K[a0+r][8g..8g+7]
    bf16x8 kf = *(const bf16x8*)(kb + ((size_t)bh * LL + a0 + r) * CH + 8 * g);
    const unsigned short* qp  = qb  + ((size_t)bh * LL + r) * CH + 8 * g;
    const unsigned short* vp0 = vtb + ((size_t)bh * CH + r) * LL + 8 * g;
    const unsigned short* vp1 = vp0 + (size_t)16 * LL;

    // lane permutation indices for the P^T gather (byte indices for bpermute)
    const int idx1 = ((((2 * g) & 3) << 4) + r) << 2;
    const int idx2 = ((((2 * g + 1) & 3) << 4) + r) << 2;
    const bool hi = (lane >= 32);   // target groups 2,3 consume tile s1

    f32x4 acc0 = {0,0,0,0}, acc1 = {0,0,0,0};
    const f32x4 zero = {0.f, 0.f, 0.f, 0.f};

    for (int q0 = 0; q0 < LL; q0 += 32) {
        bf16x8 qf0 = *(const bf16x8*)(qp + (size_t)q0 * CH);
        bf16x8 qf1 = *(const bf16x8*)(qp + (size_t)(q0 + 16) * CH);
        // S tiles: D[q local][a local]; lane holds q = 4g+i, a = r
        f32x4 s0 = __builtin_amdgcn_mfma_f32_16x16x32_bf16(qf0, kf, zero, 0, 0, 0);
        f32x4 s1 = __builtin_amdgcn_mfma_f32_16x16x32_bf16(qf1, kf, zero, 0, 0, 0);
        // P = exp(S) (normalization folded into V'); pack q-pairs as bf16x2
        unsigned int u0A = f2bf(__expf(s0[0])) | (f2bf(__expf(s0[1])) << 16);
        unsigned int u0B = f2bf(__expf(s0[2])) | (f2bf(__expf(s0[3])) << 16);
        unsigned int u1A = f2bf(__expf(s1[0])) | (f2bf(__expf(s1[1])) << 16);
        unsigned int u1B = f2bf(__expf(s1[2])) | (f2bf(__expf(s1[3])) << 16);
        // Gather P^T A-frag: lane (r,g) word w holds q pair (8g+2w, 8g+2w+1), a = r
        int a0A = __builtin_amdgcn_ds_bpermute(idx1, (int)u0A);
        int a1A = __builtin_amdgcn_ds_bpermute(idx1, (int)u1A);
        int a0B = __builtin_amdgcn_ds_bpermute(idx1, (int)u0B);
        int a1B = __builtin_amdgcn_ds_bpermute(idx1, (int)u1B);
        int c0A = __builtin_amdgcn_ds_bpermute(idx2, (int)u0A);
        int c1A = __builtin_amdgcn_ds_bpermute(idx2, (int)u1A);
        int c0B = __builtin_amdgcn_ds_bpermute(idx2, (int)u0B);
        int c1B = __builtin_amdgcn_ds_bpermute(idx2, (int)u1B);
        union { uint4 u; bf16x8 v; } pw;
        pw.u.x = (unsigned int)(hi ? a1A : a0A);
        pw.u.y = (unsigned int)(hi ? a1B : a0B);
        pw.u.z = (unsigned int)(hi ? c1A : c0A);
        pw.u.w = (unsigned int)(hi ? c1B : c0B);
        // PV: A = P^T (16a x 32q), B = V' (32q x 16d)
        bf16x8 vf0 = *(const bf16x8*)(vp0 + q0);
        bf16x8 vf1 = *(const bf16x8*)(vp1 + q0);
        acc0 = __builtin_amdgcn_mfma_f32_16x16x32_bf16(pw.v, vf0, acc0, 0, 0, 0);
        acc1 = __builtin_amdgcn_mfma_f32_16x16x32_bf16(pw.v, vf1, acc1, 0, 0, 0);
    }

    // C[a][d]: lane holds a = a0 + 4g + i, d = r (acc0) / 16+r (acc1)
    float* ob = attnT + ((size_t)b * HID + h * CH) * LL;
    *(f32x4*)(ob + (size_t)r * LL + a0 + 4 * g)        = acc0;
    *(f32x4*)(ob + (size_t)(16 + r) * LL + a0 + 4 * g) = acc1;
}

// ---------------------------------------------------------------------------
// Kernel 4: out[b,o,l] = BN( w_out @ attnT + b_out + x )
// ---------------------------------------------------------------------------
__global__ __launch_bounds__(256) void out_kernel(
        const float* __restrict__ attnT, const float* __restrict__ x,
        const float* __restrict__ w_out, const float* __restrict__ b_out,
        const float* __restrict__ bnw, const float* __restrict__ bnb,
        const float* __restrict__ bnm, const float* __restrict__ bnv,
        float* __restrict__ out) {
    __shared__ float wl[8 * 256];
    const int t = threadIdx.x;
    const int l0 = blockIdx.x * 256;
    const int o0 = blockIdx.y * 8;
    const int b  = blockIdx.z;

    const float4* ws = (const float4*)(w_out + (size_t)o0 * HID);
    float4* wd = (float4*)wl;
    #pragma unroll
    for (int r = 0; r < 2; ++r) wd[r * 256 + t] = ws[r * 256 + t];
    __syncthreads();

    float acc[8];
    #pragma unroll
    for (int j = 0; j < 8; ++j) acc[j] = 0.f;
    const float* ap = attnT + (size_t)b * HID * LL + l0 + t;
    for (int i = 0; i < HID; i += 4) {
        float a0 = ap[(size_t)(i+0) * LL];
        float a1 = ap[(size_t)(i+1) * LL];
        float a2 = ap[(size_t)(i+2) * LL];
        float a3 = ap[(size_t)(i+3) * LL];
        #pragma unroll
        for (int j = 0; j < 8; ++j) {
            float4 w4 = *(const float4*)(wl + j * 256 + i);
            acc[j] += w4.x * a0 + w4.y * a1 + w4.z * a2 + w4.w * a3;
        }
    }
    #pragma unroll
    for (int j = 0; j < 8; ++j) {
        const int o = o0 + j;
        const float inv = bnw[o] / sqrtf(bnv[o] + 1e-5f);
        const float sh  = bnb[o] - bnm[o] * inv;
        const size_t idx = ((size_t)b * CIN + o) * LL + l0 + t;
        float val = acc[j] + b_out[o] + x[idx];
        out[idx] = val * inv + sh;
    }
}

// ---------------------------------------------------------------------------
extern "C" void kernel_launch(void* const* d_in, const int* in_sizes, int n_in,
                              void* d_out, int out_size, void* d_ws, size_t ws_size,
                              hipStream_t stream) {
    const float* x      = (const float*)d_in[0];
    const float* w_qkv  = (const float*)d_in[1];
    const float* b_qkv  = (const float*)d_in[2];
    const float* w_out  = (const float*)d_in[3];
    const float* b_out  = (const float*)d_in[4];
    const float* bnw    = (const float*)d_in[5];
    const float* bnb    = (const float*)d_in[6];
    const float* bnm    = (const float*)d_in[7];
    const float* bnv    = (const float*)d_in[8];
    float* out = (float*)d_out;

    const size_t NBH = (size_t)BB * HH;          // 32
    const size_t QKV_ELEMS = NBH * LL * CH;      // 2,097,152 bf16 elems each
    unsigned short* qb  = (unsigned short*)d_ws;
    unsigned short* kb  = qb + QKV_ELEMS;
    unsigned short* vtb = kb + QKV_ELEMS;
    float* attnT = (float*)(vtb + QKV_ELEMS);    // 8 MB

    qkv_kernel<<<dim3(32, 24, BB), 256, 0, stream>>>(x, w_qkv, b_qkv, qb, kb, vtb);
    denom_mfma<<<dim3(1024), 256, 0, stream>>>(qb, kb, vtb);
    attn_mfma<<<dim3(1024), 256, 0, stream>>>(qb, kb, vtb, attnT);
    out_kernel<<<dim3(8, 16, BB), 256, 0, stream>>>(attnT, x, w_out, b_out,
                                                    bnw, bnb, bnm, bnv, out);
}

// Round 4
// 150.682 us; speedup vs baseline: 1.2526x; 1.2526x over previous
//
#include <hip/hip_runtime.h>
#include <math.h>

#define BB 4
#define CIN 128
#define LL 2048
#define HH 8
#define CH 32
#define HID 256
#define NQI 32          // 32-q iterations per q-half (2 halves of 1024 q)

typedef __attribute__((ext_vector_type(8))) __bf16 bf16x8;
typedef __attribute__((ext_vector_type(4))) float f32x4;

static __device__ __forceinline__ unsigned int f2bf(float f) {
    union { __bf16 b; unsigned short s; } u;
    u.b = (__bf16)f;
    return (unsigned int)u.s;
}
static __device__ __forceinline__ float bf2f(unsigned int s) {
    union { float f; unsigned int u; } x;
    x.u = s << 16;
    return x.f;
}

// ---------------------------------------------------------------------------
// Kernel 1: QKV 1x1 conv -> bf16 buffers.
// Q: [bh][l][d] bf16, pre-scaled by 1/sqrt(L).  K: [bh][l][d] bf16.
// V: transposed [bh][d][l] bf16.
// ---------------------------------------------------------------------------
__global__ __launch_bounds__(256) void qkv_kernel(
        const float* __restrict__ x, const float* __restrict__ w_qkv,
        const float* __restrict__ b_qkv,
        unsigned short* __restrict__ qb, unsigned short* __restrict__ kb,
        unsigned short* __restrict__ vtb) {
    __shared__ float wl[32 * 128];
    __shared__ float tr[32 * 65];
    const int t = threadIdx.x;
    const int lt = blockIdx.x;           // 0..31
    const int g  = blockIdx.y;           // 0..23 : sel*8 + h
    const int b  = blockIdx.z;
    const int sel = g >> 3, h = g & 7;
    const int obase = sel * 256 + h * 32;
    const int l0 = lt * 64;

    const float4* wsrc = (const float4*)(w_qkv + (size_t)obase * CIN);
    float4* wdst = (float4*)wl;
    #pragma unroll
    for (int r = 0; r < 4; ++r) wdst[r * 256 + t] = wsrc[r * 256 + t];
    __syncthreads();

    const int ll = t & 63, og = t >> 6;
    float acc[8] = {0.f,0.f,0.f,0.f,0.f,0.f,0.f,0.f};
    const float* xp = x + (size_t)b * CIN * LL + l0 + ll;
    for (int i = 0; i < CIN; i += 4) {
        float x0 = xp[(size_t)(i+0) * LL];
        float x1 = xp[(size_t)(i+1) * LL];
        float x2 = xp[(size_t)(i+2) * LL];
        float x3 = xp[(size_t)(i+3) * LL];
        #pragma unroll
        for (int j = 0; j < 8; ++j) {
            float4 w4 = *(const float4*)(wl + (og * 8 + j) * 128 + i);
            acc[j] += w4.x * x0 + w4.y * x1 + w4.z * x2 + w4.w * x3;
        }
    }
    const float scale = (sel == 0) ? 0.02209708691207961f : 1.0f;  // 1/sqrt(2048)
    #pragma unroll
    for (int j = 0; j < 8; ++j) {
        int oc = og * 8 + j;
        tr[oc * 65 + ll] = (acc[j] + b_qkv[obase + oc]) * scale;   // [c][l]
    }
    __syncthreads();
    if (sel == 2) {
        unsigned short* dst = vtb + ((size_t)(b * HH + h) * CH) * LL + l0;
        #pragma unroll
        for (int r = 0; r < 8; ++r) {
            int flat = r * 256 + t;           // c*64 + l
            int c = flat >> 6, l = flat & 63;
            dst[(size_t)c * LL + l] = (unsigned short)f2bf(tr[c * 65 + l]);
        }
    } else {
        unsigned short* dst = (sel == 0 ? qb : kb)
                              + ((size_t)(b * HH + h) * LL + l0) * CH;
        #pragma unroll
        for (int r = 0; r < 8; ++r) {
            int flat = r * 256 + t;           // lr*32 + c
            int c = flat & 31, lr = flat >> 5;
            dst[flat] = (unsigned short)f2bf(tr[c * 65 + lr]);
        }
    }
}

// ---------------------------------------------------------------------------
// Kernel 2: softmax denominators via MFMA, then scale V^T in place:
// vtb[bh][d][q] *= 1/sum_a exp(q . k_a).  Block owns (bh, 64-q tile).
// ---------------------------------------------------------------------------
__global__ __launch_bounds__(256) void denom_mfma(
        const unsigned short* __restrict__ qb,
        const unsigned short* __restrict__ kb,
        unsigned short* __restrict__ vtb) {
    __shared__ float zz[64];
    const int t = threadIdx.x, wave = t >> 6, lane = t & 63;
    const int id = blockIdx.x;
    const int bh = (id & 7) * 4 + ((id >> 3) >> 5);
    const int qt = (id >> 3) & 31;
    const int q0 = qt * 64 + wave * 16;
    const int r = lane & 15, g = lane >> 4;

    bf16x8 afrag = *(const bf16x8*)(qb + ((size_t)bh * LL + q0 + r) * CH + 8 * g);
    const unsigned short* kp = kb + ((size_t)bh * LL + r) * CH + 8 * g;

    float z0 = 0.f, z1 = 0.f, z2 = 0.f, z3 = 0.f;
    const f32x4 zero = {0.f, 0.f, 0.f, 0.f};
    for (int a0 = 0; a0 < LL; a0 += 64) {
        #pragma unroll
        for (int s = 0; s < 4; ++s) {
            bf16x8 bfrag = *(const bf16x8*)(kp + (size_t)(a0 + s * 16) * CH);
            f32x4 d = __builtin_amdgcn_mfma_f32_16x16x32_bf16(afrag, bfrag, zero, 0, 0, 0);
            z0 += __expf(d[0]); z1 += __expf(d[1]);
            z2 += __expf(d[2]); z3 += __expf(d[3]);
        }
    }
    #pragma unroll
    for (int m = 1; m < 16; m <<= 1) {
        z0 += __shfl_xor(z0, m); z1 += __shfl_xor(z1, m);
        z2 += __shfl_xor(z2, m); z3 += __shfl_xor(z3, m);
    }
    if (r == 0) {
        *(float4*)&zz[wave * 16 + 4 * g] =
            make_float4(1.f / z0, 1.f / z1, 1.f / z2, 1.f / z3);
    }
    __syncthreads();

    const int d = t >> 3, qo = (t & 7) * 8;
    unsigned short* vrow = vtb + ((size_t)bh * CH + d) * LL + qt * 64 + qo;
    uint4 v = *(const uint4*)vrow;
    const float* zp = zz + qo;
    unsigned int w0, w1, w2, w3;
    w0 = f2bf(bf2f(v.x & 0xFFFFu) * zp[0]) | (f2bf(bf2f(v.x >> 16) * zp[1]) << 16);
    w1 = f2bf(bf2f(v.y & 0xFFFFu) * zp[2]) | (f2bf(bf2f(v.y >> 16) * zp[3]) << 16);
    w2 = f2bf(bf2f(v.z & 0xFFFFu) * zp[4]) | (f2bf(bf2f(v.z >> 16) * zp[5]) << 16);
    w3 = f2bf(bf2f(v.w & 0xFFFFu) * zp[6]) | (f2bf(bf2f(v.w >> 16) * zp[7]) << 16);
    *(uint4*)vrow = make_uint4(w0, w1, w2, w3);
}

// ---------------------------------------------------------------------------
// Kernel 3: attn^T via MFMA, software-pipelined per-wave LDS P^T bounce.
// attnT_part[qh][b][h*32+d][a] = sum_{q in half} P[q,a] V'[q,d]
// Wave: 32 a-cols x 32 d.  Stage n: read P(n) from buf, compute S(n+1),
// write P(n+1) to other buf, PV(n).  Counted lgkm waits come from compiler.
// ---------------------------------------------------------------------------
__global__ __launch_bounds__(256, 4) void attn_mfma(
        const unsigned short* __restrict__ qb,
        const unsigned short* __restrict__ kb,
        const unsigned short* __restrict__ vtb,
        float* __restrict__ attnT) {
    __shared__ unsigned short ptA[4][32][40];   // per-wave P^T, stride 40 (80B)
    __shared__ unsigned short ptB[4][32][40];
    const int t = threadIdx.x, wave = t >> 6, lane = t & 63;
    const int r = lane & 15, g = lane >> 4;
    const int id = blockIdx.x;
    const int bh = (id & 7) * 4 + ((id >> 3) >> 5);
    const int rest = (id >> 3) & 31;
    const int qh = rest & 1, at = rest >> 1;    // at 0..15
    const int b = bh >> 3, h = bh & 7;
    const int a0 = at * 128 + wave * 32;
    const int q00 = qh * 1024;

    const unsigned short* kp = kb + ((size_t)bh * LL + a0 + r) * CH + 8 * g;
    const bf16x8 kf0 = *(const bf16x8*)kp;
    const bf16x8 kf1 = *(const bf16x8*)(kp + 16 * CH);
    const unsigned short* qp  = qb  + ((size_t)bh * LL + q00 + r) * CH + 8 * g;
    const unsigned short* vp0 = vtb + ((size_t)bh * CH + r) * LL + q00 + 8 * g;
    const unsigned short* vp1 = vp0 + (size_t)16 * LL;

    unsigned short* const bA = &ptA[wave][0][0];
    unsigned short* const bB = &ptB[wave][0][0];
    const int rd0 = r * 40 + 8 * g, rd1 = rd0 + 640;
    const int wr0 = r * 40 + 4 * g, wr1 = wr0 + 640;

    f32x4 acc00 = {0,0,0,0}, acc01 = {0,0,0,0}, acc10 = {0,0,0,0}, acc11 = {0,0,0,0};
    const f32x4 zero = {0.f, 0.f, 0.f, 0.f};

#define PACK2(s) make_uint2( \
        f2bf(__expf((s)[0])) | (f2bf(__expf((s)[1])) << 16), \
        f2bf(__expf((s)[2])) | (f2bf(__expf((s)[3])) << 16))

    // ---- prologue: compute & store P(0), prefetch qf(1), load vf(0) ----
    bf16x8 qn0 = *(const bf16x8*)qp;
    bf16x8 qn1 = *(const bf16x8*)(qp + 16 * CH);
    {
        f32x4 s00 = __builtin_amdgcn_mfma_f32_16x16x32_bf16(qn0, kf0, zero, 0, 0, 0);
        f32x4 s01 = __builtin_amdgcn_mfma_f32_16x16x32_bf16(qn0, kf1, zero, 0, 0, 0);
        f32x4 s10 = __builtin_amdgcn_mfma_f32_16x16x32_bf16(qn1, kf0, zero, 0, 0, 0);
        f32x4 s11 = __builtin_amdgcn_mfma_f32_16x16x32_bf16(qn1, kf1, zero, 0, 0, 0);
        *(uint2*)(bA + wr0)      = PACK2(s00);
        *(uint2*)(bA + wr1)      = PACK2(s01);
        *(uint2*)(bA + wr0 + 16) = PACK2(s10);
        *(uint2*)(bA + wr1 + 16) = PACK2(s11);
    }
    bf16x8 vc0 = *(const bf16x8*)vp0;
    bf16x8 vc1 = *(const bf16x8*)vp1;
    qn0 = *(const bf16x8*)(qp + 32 * CH);
    qn1 = *(const bf16x8*)(qp + 48 * CH);
    const unsigned short* qpn  = qp + 64 * CH;   // q frags for iter 2
    const unsigned short* vpn0 = vp0 + 32;       // v frags for iter 1
    const unsigned short* vpn1 = vp1 + 32;

#define STAGE(RD, WR, DOS, DOQ, DOV) do { \
    bf16x8 pa0 = *(const bf16x8*)((RD) + rd0); \
    bf16x8 pa1 = *(const bf16x8*)((RD) + rd1); \
    if (DOS) { \
        f32x4 s00 = __builtin_amdgcn_mfma_f32_16x16x32_bf16(qn0, kf0, zero, 0, 0, 0); \
        f32x4 s01 = __builtin_amdgcn_mfma_f32_16x16x32_bf16(qn0, kf1, zero, 0, 0, 0); \
        f32x4 s10 = __builtin_amdgcn_mfma_f32_16x16x32_bf16(qn1, kf0, zero, 0, 0, 0); \
        f32x4 s11 = __builtin_amdgcn_mfma_f32_16x16x32_bf16(qn1, kf1, zero, 0, 0, 0); \
        *(uint2*)((WR) + wr0)      = PACK2(s00); \
        *(uint2*)((WR) + wr1)      = PACK2(s01); \
        *(uint2*)((WR) + wr0 + 16) = PACK2(s10); \
        *(uint2*)((WR) + wr1 + 16) = PACK2(s11); \
    } \
    if (DOQ) { \
        qn0 = *(const bf16x8*)qpn; \
        qn1 = *(const bf16x8*)(qpn + 16 * CH); \
        qpn += 32 * CH; \
    } \
    acc00 = __builtin_amdgcn_mfma_f32_16x16x32_bf16(pa0, vc0, acc00, 0, 0, 0); \
    acc01 = __builtin_amdgcn_mfma_f32_16x16x32_bf16(pa0, vc1, acc01, 0, 0, 0); \
    acc10 = __builtin_amdgcn_mfma_f32_16x16x32_bf16(pa1, vc0, acc10, 0, 0, 0); \
    acc11 = __builtin_amdgcn_mfma_f32_16x16x32_bf16(pa1, vc1, acc11, 0, 0, 0); \
    if (DOV) { \
        vc0 = *(const bf16x8*)vpn0; \
        vc1 = *(const bf16x8*)vpn1; \
        vpn0 += 32; vpn1 += 32; \
    } \
} while (0)

    for (int nn = 0; nn < 15; ++nn) {
        STAGE(bA, bB, 1, 1, 1);    // even stage n=2nn
        STAGE(bB, bA, 1, 1, 1);    // odd stage n=2nn+1
    }
    STAGE(bA, bB, 1, 0, 1);        // n=30: compute/write P(31), load vf(31)
    STAGE(bB, bA, 0, 0, 0);        // n=31: PV only

#undef STAGE
#undef PACK2

    float* ob = attnT + ((size_t)qh * BB * HID + (size_t)b * HID + h * CH) * LL;
    *(f32x4*)(ob + (size_t)(r     ) * LL + a0 +      4 * g) = acc00;  // a-sub0, d=r
    *(f32x4*)(ob + (size_t)(16 + r) * LL + a0 +      4 * g) = acc01;  // a-sub0, d=16+r
    *(f32x4*)(ob + (size_t)(r     ) * LL + a0 + 16 + 4 * g) = acc10;  // a-sub1, d=r
    *(f32x4*)(ob + (size_t)(16 + r) * LL + a0 + 16 + 4 * g) = acc11;  // a-sub1, d=16+r
}

// ---------------------------------------------------------------------------
// Kernel 4: out[b,o,l] = BN( w_out @ (attnT0+attnT1) + b_out + x )
// ---------------------------------------------------------------------------
__global__ __launch_bounds__(256) void out_kernel(
        const float* __restrict__ attnT, const float* __restrict__ x,
        const float* __restrict__ w_out, const float* __restrict__ b_out,
        const float* __restrict__ bnw, const float* __restrict__ bnb,
        const float* __restrict__ bnm, const float* __restrict__ bnv,
        float* __restrict__ out) {
    __shared__ float wl[8 * 256];
    const int t = threadIdx.x;
    const int l0 = blockIdx.x * 256;
    const int o0 = blockIdx.y * 8;
    const int b  = blockIdx.z;

    const float4* ws = (const float4*)(w_out + (size_t)o0 * HID);
    float4* wd = (float4*)wl;
    #pragma unroll
    for (int r = 0; r < 2; ++r) wd[r * 256 + t] = ws[r * 256 + t];
    __syncthreads();

    float acc[8];
    #pragma unroll
    for (int j = 0; j < 8; ++j) acc[j] = 0.f;
    const float* ap0 = attnT + (size_t)b * HID * LL + l0 + t;
    const float* ap1 = ap0 + (size_t)BB * HID * LL;
    for (int i = 0; i < HID; i += 4) {
        float a0 = ap0[(size_t)(i+0) * LL] + ap1[(size_t)(i+0) * LL];
        float a1 = ap0[(size_t)(i+1) * LL] + ap1[(size_t)(i+1) * LL];
        float a2 = ap0[(size_t)(i+2) * LL] + ap1[(size_t)(i+2) * LL];
        float a3 = ap0[(size_t)(i+3) * LL] + ap1[(size_t)(i+3) * LL];
        #pragma unroll
        for (int j = 0; j < 8; ++j) {
            float4 w4 = *(const float4*)(wl + j * 256 + i);
            acc[j] += w4.x * a0 + w4.y * a1 + w4.z * a2 + w4.w * a3;
        }
    }
    #pragma unroll
    for (int j = 0; j < 8; ++j) {
        const int o = o0 + j;
        const float inv = bnw[o] / sqrtf(bnv[o] + 1e-5f);
        const float sh  = bnb[o] - bnm[o] * inv;
        const size_t idx = ((size_t)b * CIN + o) * LL + l0 + t;
        float val = acc[j] + b_out[o] + x[idx];
        out[idx] = val * inv + sh;
    }
}

// ---------------------------------------------------------------------------
extern "C" void kernel_launch(void* const* d_in, const int* in_sizes, int n_in,
                              void* d_out, int out_size, void* d_ws, size_t ws_size,
                              hipStream_t stream) {
    const float* x      = (const float*)d_in[0];
    const float* w_qkv  = (const float*)d_in[1];
    const float* b_qkv  = (const float*)d_in[2];
    const float* w_out  = (const float*)d_in[3];
    const float* b_out  = (const float*)d_in[4];
    const float* bnw    = (const float*)d_in[5];
    const float* bnb    = (const float*)d_in[6];
    const float* bnm    = (const float*)d_in[7];
    const float* bnv    = (const float*)d_in[8];
    float* out = (float*)d_out;

    const size_t NBH = (size_t)BB * HH;          // 32
    const size_t QKV_ELEMS = NBH * LL * CH;      // 2,097,152 bf16 elems each
    unsigned short* qb  = (unsigned short*)d_ws;
    unsigned short* kb  = qb + QKV_ELEMS;
    unsigned short* vtb = kb + QKV_ELEMS;
    float* attnT = (float*)(vtb + QKV_ELEMS);    // 2 x 8 MB partials

    qkv_kernel<<<dim3(32, 24, BB), 256, 0, stream>>>(x, w_qkv, b_qkv, qb, kb, vtb);
    denom_mfma<<<dim3(1024), 256, 0, stream>>>(qb, kb, vtb);
    attn_mfma<<<dim3(1024), 256, 0, stream>>>(qb, kb, vtb, attnT);
    out_kernel<<<dim3(8, 16, BB), 256, 0, stream>>>(attnT, x, w_out, b_out,
                                                    bnw, bnb, bnm, bnv, out);
}